// Round 4
// baseline (14891.917 us; speedup 1.0000x reference)
//
#include <hip/hip_runtime.h>
#include <cstddef>

#define EPSQ 1e-4f
#define S_TOT 512
#define BB 256
#define DH 256
#define NC 512

// ws offsets (in floats)
#define OFF_KIH 0
#define OFF_KHH 131072
#define OFF_KPH 262144
#define OFF_KPC 393216
#define OFF_BA  524288
#define OFF_BP  524800
#define OFF_H   525312
#define OFF_AC  590848
#define OFF_PH  721920
#define OFF_UPD 852992
#define OFF_CTR 984064
#define OFF_X2  985088

union F4 { float4 v; float f[4]; };
union F2 { float2 v; float f[2]; };

// Hamilton-product component/sign tables: K[a*64+m][c*128+g] = sign[c][a]*w_{comp[c][a]}[m][g]
__constant__ int   d_comp[16] = {0,1,2,3, 1,0,3,2, 2,3,0,1, 3,2,1,0};
__constant__ float d_sign[16] = {1.f,-1.f,-1.f,-1.f, 1.f,1.f,-1.f,1.f, 1.f,1.f,1.f,-1.f, 1.f,-1.f,1.f,1.f};

__global__ void build_qk(const float* __restrict__ wr, const float* __restrict__ wi,
                         const float* __restrict__ wj, const float* __restrict__ wk,
                         float* __restrict__ K) {
  int idx = blockIdx.x * blockDim.x + threadIdx.x;
  if (idx >= 131072) return;
  int col = idx & 511, row = idx >> 9;
  int a = row >> 6, m = row & 63;
  int c = col >> 7, g = col & 127;
  int tt = c * 4 + a;
  int cc = d_comp[tt];
  const float* s = (cc == 0) ? wr : (cc == 1) ? wi : (cc == 2) ? wj : wk;
  K[idx] = d_sign[tt] * s[m * 128 + g];
}

__global__ void build_bias(const float* __restrict__ b1, const float* __restrict__ b2,
                           const float* __restrict__ b3, const float* __restrict__ b4,
                           float* __restrict__ bA, float* __restrict__ bP) {
  int i = blockIdx.x * blockDim.x + threadIdx.x;
  if (i < 512) { bA[i] = b1[i] + b2[i]; bP[i] = b3[i] + b4[i]; }
}

__global__ void zero_ctr(int* ctr) {
  int i = blockIdx.x * blockDim.x + threadIdx.x;
  if (i < 1024) ctr[i] = 0;
}

// X2[m][n] = sum_k A[m][k]*W[k][n] + bA[n];  A:[M][256], W:[256][512]
__global__ __launch_bounds__(256) void gemm_x2(
    const float* __restrict__ A, const float* __restrict__ W,
    const float* __restrict__ bA, float* __restrict__ C) {
  __shared__ float As[16][68];
  __shared__ float Ws[16][68];
  const int tid = threadIdx.x;
  const int nt = blockIdx.x, mt = blockIdx.y;
  const int m0 = mt * 64, n0 = nt * 64;
  const int tx = tid & 15, ty = tid >> 4;
  float acc[4][4];
#pragma unroll
  for (int i = 0; i < 4; i++)
#pragma unroll
    for (int j = 0; j < 4; j++) acc[i][j] = 0.f;
  const int lr = tid >> 2, lk = (tid & 3) * 4;
  const int wkr = tid >> 4, wn = (tid & 15) * 4;
  for (int k0 = 0; k0 < 256; k0 += 16) {
    float4 a4 = *(const float4*)(A + (size_t)(m0 + lr) * 256 + k0 + lk);
    float4 w4 = *(const float4*)(W + (size_t)(k0 + wkr) * 512 + n0 + wn);
    As[lk + 0][lr] = a4.x; As[lk + 1][lr] = a4.y; As[lk + 2][lr] = a4.z; As[lk + 3][lr] = a4.w;
    *(float4*)(&Ws[wkr][wn]) = w4;
    __syncthreads();
#pragma unroll
    for (int k = 0; k < 16; k++) {
      F4 av, wv;
      av.v = *(const float4*)(&As[k][ty * 4]);
      wv.v = *(const float4*)(&Ws[k][tx * 4]);
#pragma unroll
      for (int i = 0; i < 4; i++)
#pragma unroll
        for (int j = 0; j < 4; j++) acc[i][j] += av.f[i] * wv.f[j];
    }
    __syncthreads();
  }
  F4 b4; b4.v = *(const float4*)(bA + n0 + tx * 4);
#pragma unroll
  for (int i = 0; i < 4; i++) {
    int m = m0 + ty * 4 + i;
    F4 o;
#pragma unroll
    for (int j = 0; j < 4; j++) o.f[j] = acc[i][j] + b4.f[j];
    *(float4*)(C + (size_t)m * 512 + n0 + tx * 4) = o.v;
  }
}

// Agent-scope relaxed atomics for exchanged data: device-coherent point,
// no cache-maintenance fences in the hot loop. Correct regardless of
// block->XCD mapping.
__device__ __forceinline__ float gload(const float* p) {
  return __hip_atomic_load((float*)p, __ATOMIC_RELAXED, __HIP_MEMORY_SCOPE_AGENT);
}
__device__ __forceinline__ F2 gload2(const float* p) {
  union { unsigned long long u; F2 f2; } c;
  c.u = __hip_atomic_load((const unsigned long long*)p, __ATOMIC_RELAXED, __HIP_MEMORY_SCOPE_AGENT);
  return c.f2;
}
__device__ __forceinline__ void gstore(float* p, float v) {
  __hip_atomic_store(p, v, __ATOMIC_RELAXED, __HIP_MEMORY_SCOPE_AGENT);
}
__device__ __forceinline__ void gstore2(float* p, float a, float b) {
  union { unsigned long long u; float f[2]; } c;
  c.f[0] = a; c.f[1] = b;
  __hip_atomic_store((unsigned long long*)p, c.u, __ATOMIC_RELAXED, __HIP_MEMORY_SCOPE_AGENT);
}

// Split barrier, 4 sub-counters per cluster (8 arrivals each, on separate
// 64B lines -> RMWs proceed in parallel at the LLC). arrive: drain own
// stores + block-sync + add. wait: spin on the sum (monotone across steps).
__device__ __forceinline__ void cl_arrive(int* ctr_mine) {
  asm volatile("s_waitcnt vmcnt(0)" ::: "memory");
  __syncthreads();
  if (threadIdx.x == 0)
    __hip_atomic_fetch_add(ctr_mine, 1, __ATOMIC_RELAXED, __HIP_MEMORY_SCOPE_AGENT);
}
__device__ __forceinline__ void cl_wait(int* ctr_cluster, int target_sum) {
  if (threadIdx.x == 0) {
    for (;;) {
      int s = __hip_atomic_load(ctr_cluster +  0, __ATOMIC_RELAXED, __HIP_MEMORY_SCOPE_AGENT)
            + __hip_atomic_load(ctr_cluster + 16, __ATOMIC_RELAXED, __HIP_MEMORY_SCOPE_AGENT)
            + __hip_atomic_load(ctr_cluster + 32, __ATOMIC_RELAXED, __HIP_MEMORY_SCOPE_AGENT)
            + __hip_atomic_load(ctr_cluster + 48, __ATOMIC_RELAXED, __HIP_MEMORY_SCOPE_AGENT);
      if (s >= target_sum) break;
    }
  }
  __syncthreads();
}

// ---- phase bodies ----

// Phase1: 32-col slice of [ac | ph] for the cluster's 16 rows, K=256.
// Weights read straight from L2 (Wg = Khh/Kph column slice); the additive
// term (X2 or bias) is prefetched before the k-loop.
__device__ __forceinline__ void do_p1(
    const float* __restrict__ Wg, const float (* __restrict__ hN)[20],
    const float* __restrict__ X2, const float* __restrict__ bP,
    float* __restrict__ ac_g, float* __restrict__ ph_g,
    int t, int row0, int cg, int wave, int lane) {
  const int tile = lane & 7;
  const int cq = tile & 1;
  const int rq = (tile >> 1) & 3;
  const int ks = lane >> 3;            // 8-way k split
  const int col0 = wave * 8 + cq * 4;  // local col quad base (0..28)
  const int b2 = ks >> 2;
  const int row = row0 + rq * 4 + (ks & 3);
  // prefetch additive term + destination
  float add0, add1; float* dst;
  if (cg < 16) {
    const int colA = cg * 32 + col0 + 2 * b2;
    F2 x2; x2.v = *(const float2*)(X2 + ((size_t)t * BB + row) * 512 + colA);
    add0 = x2.f[0]; add1 = x2.f[1];
    dst = ac_g + (size_t)row * 512 + colA;
  } else {
    const int colP = (cg - 16) * 32 + col0 + 2 * b2;
    add0 = bP[colP]; add1 = bP[colP + 1];
    dst = ph_g + (size_t)row * 512 + colP;
  }
  const float* wp = Wg + col0;
  float acc[4][4];
#pragma unroll
  for (int i = 0; i < 4; i++)
#pragma unroll
    for (int j = 0; j < 4; j++) acc[i][j] = 0.f;
#pragma unroll 8
  for (int i = 0; i < 32; i++) {
    const int k = ks + 8 * i;
    F4 w4, h4;
    w4.v = *(const float4*)(wp + (size_t)k * 512);
    h4.v = *(const float4*)(&hN[k][rq * 4]);
#pragma unroll
    for (int ii = 0; ii < 4; ii++)
#pragma unroll
      for (int jj = 0; jj < 4; jj++) acc[ii][jj] += h4.f[ii] * w4.f[jj];
  }
  // select-exchange reduction over ks bits (lane bits 3,4,5)
  const int b0 = ks & 1, b1 = (ks >> 1) & 1;
  float r8[2][4];
#pragma unroll
  for (int i2 = 0; i2 < 2; i2++)
#pragma unroll
    for (int jj = 0; jj < 4; jj++) {
      float keep = b0 ? acc[2 * i2 + 1][jj] : acc[2 * i2][jj];
      float give = b0 ? acc[2 * i2][jj] : acc[2 * i2 + 1][jj];
      r8[i2][jj] = keep + __shfl_xor(give, 8);
    }
  float r4[4];
#pragma unroll
  for (int jj = 0; jj < 4; jj++) {
    float keep = b1 ? r8[1][jj] : r8[0][jj];
    float give = b1 ? r8[0][jj] : r8[1][jj];
    r4[jj] = keep + __shfl_xor(give, 16);
  }
  float r2[2];
#pragma unroll
  for (int j2 = 0; j2 < 2; j2++) {
    float keep = b2 ? r4[2 + j2] : r4[j2];
    float give = b2 ? r4[j2] : r4[2 + j2];
    r2[j2] = keep + __shfl_xor(give, 32);
  }
  gstore2(dst, r2[0] + add0, r2[1] + add1);
}

// Phase2a: build candT for the cluster's 16 rows (redundant per block).
__device__ __forceinline__ void do_p2a(
    float (* __restrict__ cT)[20], const float* __restrict__ ac_g,
    int row0, int tid) {
  const int r = tid & 15;
  const int q0 = (tid >> 4) * 4;
  const float* ab = ac_g + (size_t)(row0 + r) * 512;
  F4 am[4], cn[4];
#pragma unroll
  for (int a = 0; a < 4; a++) {
    F2 x = gload2(ab + a * 128 + q0);
    F2 y = gload2(ab + a * 128 + q0 + 2);
    am[a].f[0] = x.f[0]; am[a].f[1] = x.f[1]; am[a].f[2] = y.f[0]; am[a].f[3] = y.f[1];
    F2 u = gload2(ab + a * 128 + 64 + q0);
    F2 v = gload2(ab + a * 128 + 64 + q0 + 2);
    cn[a].f[0] = u.f[0]; cn[a].f[1] = u.f[1]; cn[a].f[2] = v.f[0]; cn[a].f[3] = v.f[1];
  }
#pragma unroll
  for (int j = 0; j < 4; j++) {
    const int q = q0 + j;
    float ag = sqrtf(am[0].f[j] * am[0].f[j] + am[1].f[j] * am[1].f[j] +
                     am[2].f[j] * am[2].f[j] + am[3].f[j] * am[3].f[j]);
    float t0 = cn[0].f[j] * ag, t1 = cn[1].f[j] * ag;
    float t2 = cn[2].f[j] * ag, t3 = cn[3].f[j] * ag;
    float mc = sqrtf(t0 * t0 + t1 * t1 + t2 * t2 + t3 * t3);
    float inv = 1.f / (mc + EPSQ);
    cT[0 * 64 + q][r] = t0 * inv;
    cT[1 * 64 + q][r] = t1 * inv;
    cT[2 * 64 + q][r] = t2 * inv;
    cT[3 * 64 + q][r] = t3 * inv;
  }
}

// Phase2b: 16-col slice of upd for 16 rows, K=256. Kpc from L2; ph
// prefetched before the k-loop.
__device__ __forceinline__ void do_p2b(
    const float* __restrict__ Wpg, const float (* __restrict__ cT)[20],
    const float* __restrict__ ph_g, float* __restrict__ upd_g,
    int row0, int cg, int wave, int lane) {
  const int rq = lane & 3;
  const int ks = lane >> 2;            // 16-way k split
  const int b0 = ks & 1, b1 = (ks >> 1) & 1, b2 = (ks >> 2) & 1, b3 = ks >> 3;
  const int row = row0 + rq * 4 + (ks & 3);
  const int colP = cg * 16 + wave * 4 + 2 * b3 + b2;
  float phv = gload(ph_g + (size_t)row * 512 + colP);   // prefetch
  const float* wp = Wpg + wave * 4;
  float acc[4][4];
#pragma unroll
  for (int i = 0; i < 4; i++)
#pragma unroll
    for (int j = 0; j < 4; j++) acc[i][j] = 0.f;
#pragma unroll 4
  for (int i = 0; i < 16; i++) {
    const int k = ks + 16 * i;
    F4 w4, c4;
    w4.v = *(const float4*)(wp + (size_t)k * 512);
    c4.v = *(const float4*)(&cT[k][rq * 4]);
#pragma unroll
    for (int ii = 0; ii < 4; ii++)
#pragma unroll
      for (int jj = 0; jj < 4; jj++) acc[ii][jj] += c4.f[ii] * w4.f[jj];
  }
  float r8[2][4];
#pragma unroll
  for (int i2 = 0; i2 < 2; i2++)
#pragma unroll
    for (int jj = 0; jj < 4; jj++) {
      float keep = b0 ? acc[2 * i2 + 1][jj] : acc[2 * i2][jj];
      float give = b0 ? acc[2 * i2][jj] : acc[2 * i2 + 1][jj];
      r8[i2][jj] = keep + __shfl_xor(give, 4);
    }
  float r4[4];
#pragma unroll
  for (int jj = 0; jj < 4; jj++) {
    float keep = b1 ? r8[1][jj] : r8[0][jj];
    float give = b1 ? r8[0][jj] : r8[1][jj];
    r4[jj] = keep + __shfl_xor(give, 8);
  }
  float rr[2];
#pragma unroll
  for (int m = 0; m < 2; m++) {
    float keep = b2 ? r4[2 * m + 1] : r4[2 * m];
    float give = b2 ? r4[2 * m] : r4[2 * m + 1];
    rr[m] = keep + __shfl_xor(give, 16);
  }
  float vfin;
  {
    float keep = b3 ? rr[1] : rr[0];
    float give = b3 ? rr[0] : rr[1];
    vfin = keep + __shfl_xor(give, 32);
  }
  gstore(upd_g + (size_t)row * 512 + colP, vfin + phv);
}

// Phase3: a_new + output + renormalize into hNT (redundant per block).
__device__ __forceinline__ void do_p3(
    float (* __restrict__ hN)[20], const float (* __restrict__ cT)[20],
    const float* __restrict__ upd_g, float* __restrict__ out,
    float* __restrict__ h_out, float* __restrict__ hT,
    int row0, int cg, int tid, int t, int steps) {
  const int r = tid & 15;
  const int q0 = (tid >> 4) * 4;
  const float* ur = upd_g + (size_t)(row0 + r) * 512;
  F4 u0, u1, u2, u3, u4, u5, u7;
  {
    F2 a, b;
    a = gload2(ur + 0 * 64 + q0); b = gload2(ur + 0 * 64 + q0 + 2);
    u0.f[0] = a.f[0]; u0.f[1] = a.f[1]; u0.f[2] = b.f[0]; u0.f[3] = b.f[1];
    a = gload2(ur + 1 * 64 + q0); b = gload2(ur + 1 * 64 + q0 + 2);
    u1.f[0] = a.f[0]; u1.f[1] = a.f[1]; u1.f[2] = b.f[0]; u1.f[3] = b.f[1];
    a = gload2(ur + 2 * 64 + q0); b = gload2(ur + 2 * 64 + q0 + 2);
    u2.f[0] = a.f[0]; u2.f[1] = a.f[1]; u2.f[2] = b.f[0]; u2.f[3] = b.f[1];
    a = gload2(ur + 3 * 64 + q0); b = gload2(ur + 3 * 64 + q0 + 2);
    u3.f[0] = a.f[0]; u3.f[1] = a.f[1]; u3.f[2] = b.f[0]; u3.f[3] = b.f[1];
    a = gload2(ur + 4 * 64 + q0); b = gload2(ur + 4 * 64 + q0 + 2);
    u4.f[0] = a.f[0]; u4.f[1] = a.f[1]; u4.f[2] = b.f[0]; u4.f[3] = b.f[1];
    a = gload2(ur + 5 * 64 + q0); b = gload2(ur + 5 * 64 + q0 + 2);
    u5.f[0] = a.f[0]; u5.f[1] = a.f[1]; u5.f[2] = b.f[0]; u5.f[3] = b.f[1];
    a = gload2(ur + 7 * 64 + q0); b = gload2(ur + 7 * 64 + q0 + 2);
    u7.f[0] = a.f[0]; u7.f[1] = a.f[1]; u7.f[2] = b.f[0]; u7.f[3] = b.f[1];
  }
  F4 anew[4]; float invm[4];
#pragma unroll
  for (int j = 0; j < 4; j++) {
    const int q = q0 + j;
    float mh = sqrtf(u0.f[j] * u0.f[j] + 2.f * u2.f[j] * u2.f[j] + u4.f[j] * u4.f[j]);
    float mc = sqrtf(u1.f[j] * u1.f[j] + u3.f[j] * u3.f[j] +
                     u5.f[j] * u5.f[j] + u7.f[j] * u7.f[j]);
    float s = 0.f;
#pragma unroll
    for (int a = 0; a < 4; a++) {
      float av = hN[a * 64 + q][r] * mh + cT[a * 64 + q][r] * mc;
      anew[a].f[j] = av;
      s += av * av;
    }
    invm[j] = 1.f / (sqrtf(s) + EPSQ);
  }
  if (cg == 0) {
#pragma unroll
    for (int a = 0; a < 4; a++)
      *(float4*)(out + ((size_t)t * BB + row0 + r) * 256 + a * 64 + q0) = anew[a].v;
    if (t == steps - 1) {
#pragma unroll
      for (int a = 0; a < 4; a++)
        *(float4*)(h_out + (size_t)(row0 + r) * 256 + a * 64 + q0) = anew[a].v;
      if (hT != nullptr) {
#pragma unroll
        for (int a = 0; a < 4; a++)
          *(float4*)(hT + (size_t)(row0 + r) * 256 + a * 64 + q0) = anew[a].v;
      }
    }
  }
#pragma unroll
  for (int j = 0; j < 4; j++) {
    const int q = q0 + j;
#pragma unroll
    for (int a = 0; a < 4; a++)
      hN[a * 64 + q][r] = anew[a].f[j] * invm[j];
  }
}

// Persistent recurrent kernel. 512 blocks x 256 threads, 2 blocks/CU.
// 16 clusters x 32 blocks: cluster = blk&15, cg = blk>>4 in [0,32).
// cg<16: 32-col ac slice (K_hh); cg>=16: 32-col ph slice (K_ph);
// all blocks: 16-col upd slice (K_pc). Weights are read from L2 (plain
// cached loads, 1.5 MB total, L2-resident); LDS holds only the two state
// arrays (40 KB/block) so 2 blocks always co-reside per CU: one block's
// compute hides the other's barrier/LLC latency (independent clusters).
__global__ __launch_bounds__(256, 2) void qru_seq(
    const float* __restrict__ X2,   // [steps][B][512]
    const float* __restrict__ h_in, // [B][256] raw h
    const float* __restrict__ Khh, const float* __restrict__ Kph,
    const float* __restrict__ Kpc, const float* __restrict__ bP,
    float* __restrict__ ac_g, float* __restrict__ ph_g, float* __restrict__ upd_g,
    float* __restrict__ h_out, float* __restrict__ out, float* __restrict__ hT,
    int* __restrict__ ctr_base, int t0, int steps) {
  __shared__ __align__(16) float hNT[256][20];    // 20KB, [q][r] padded
  __shared__ __align__(16) float candT[256][20];  // 20KB, [q][r] padded

  const int tid = threadIdx.x;
  const int blk = blockIdx.x;
  const int cluster = blk & 15;
  const int cg = blk >> 4;              // 0..31
  const int row0 = cluster * 16;
  int* ctrc = ctr_base + cluster * 64;  // 4 sub-counters per cluster
  int* ctrm = ctrc + (cg & 3) * 16;     // this block's sub-counter (64B apart)

  const float* Wg  = (cg < 16) ? (Khh + cg * 32) : (Kph + (cg - 16) * 32);
  const float* Wpg = Kpc + cg * 16;

  // ---- init hNT = normalize(h_in) ----
  {
    const int r = tid & 15;
    const int q0 = (tid >> 4) * 4;
    F4 v[4];
#pragma unroll
    for (int a = 0; a < 4; a++)
      v[a].v = *(const float4*)(h_in + (size_t)(row0 + r) * 256 + a * 64 + q0);
#pragma unroll
    for (int j = 0; j < 4; j++) {
      const int q = q0 + j;
      float ss = v[0].f[j] * v[0].f[j] + v[1].f[j] * v[1].f[j] +
                 v[2].f[j] * v[2].f[j] + v[3].f[j] * v[3].f[j];
      float inv = 1.f / (sqrtf(ss) + EPSQ);
#pragma unroll
      for (int a = 0; a < 4; a++) hNT[a * 64 + q][r] = v[a].f[j] * inv;
    }
  }
  __syncthreads();

  const int wave = tid >> 6;
  const int lane = tid & 63;

  for (int t = 0; t < steps; ++t) {
    const int g = t0 + t;
    do_p1(Wg, hNT, X2, bP, ac_g, ph_g, t, row0, cg, wave, lane);
    cl_arrive(ctrm);
    cl_wait(ctrc, (2 * g + 1) * 32);
    do_p2a(candT, ac_g, row0, tid);
    __syncthreads();
    do_p2b(Wpg, candT, ph_g, upd_g, row0, cg, wave, lane);
    cl_arrive(ctrm);
    cl_wait(ctrc, (2 * g + 2) * 32);
    do_p3(hNT, candT, upd_g, out, h_out, hT, row0, cg, tid, t, steps);
    __syncthreads();   // hNT/candT stable before next P1 / next P2a
  }
}

extern "C" void kernel_launch(void* const* d_in, const int* in_sizes, int n_in,
                              void* d_out, int out_size, void* d_ws, size_t ws_size,
                              hipStream_t stream) {
  const float* input = (const float*)d_in[0];
  const float* hx = (const float*)d_in[1];
  float* ws = (float*)d_ws;
  float* Kih = ws + OFF_KIH;
  float* Khh = ws + OFF_KHH;
  float* Kph = ws + OFF_KPH;
  float* Kpc = ws + OFF_KPC;
  float* bA = ws + OFF_BA;
  float* bP = ws + OFF_BP;
  float* Hst = ws + OFF_H;
  float* acb = ws + OFF_AC;
  float* phb = ws + OFF_PH;
  float* updb = ws + OFF_UPD;
  int*   ctrb = (int*)(ws + OFF_CTR);
  float* X2b = ws + OFF_X2;

  build_qk<<<512, 256, 0, stream>>>((const float*)d_in[2], (const float*)d_in[3],
                                    (const float*)d_in[4], (const float*)d_in[5], Kih);
  build_qk<<<512, 256, 0, stream>>>((const float*)d_in[6], (const float*)d_in[7],
                                    (const float*)d_in[8], (const float*)d_in[9], Khh);
  build_qk<<<512, 256, 0, stream>>>((const float*)d_in[10], (const float*)d_in[11],
                                    (const float*)d_in[12], (const float*)d_in[13], Kpc);
  build_qk<<<512, 256, 0, stream>>>((const float*)d_in[14], (const float*)d_in[15],
                                    (const float*)d_in[16], (const float*)d_in[17], Kph);
  build_bias<<<2, 256, 0, stream>>>((const float*)d_in[18], (const float*)d_in[19],
                                    (const float*)d_in[20], (const float*)d_in[21], bA, bP);
  zero_ctr<<<4, 256, 0, stream>>>(ctrb);

  // pick largest chunk of steps whose X2 buffer fits in ws
  int CHv = 64;
  while (CHv > 8 && ((size_t)OFF_X2 + (size_t)CHv * BB * NC) * 4 > ws_size) CHv >>= 1;
  const int nch = S_TOT / CHv;

  for (int c = 0; c < nch; ++c) {
    gemm_x2<<<dim3(8, CHv * 4), 256, 0, stream>>>(
        input + (size_t)c * CHv * BB * DH, Kih, bA, X2b);

    const float* X2p = X2b;
    const float* hsrc = (c == 0) ? hx : (const float*)Hst;
    const float* Khhp = Khh; const float* Kphp = Kph; const float* Kpcp = Kpc;
    const float* bPp = bP;
    float* acp = acb; float* php = phb; float* updp = updb; float* hop = Hst;
    float* outp = (float*)d_out + (size_t)c * CHv * BB * DH;
    float* hTp = (c == nch - 1) ? ((float*)d_out + (size_t)S_TOT * BB * DH) : nullptr;
    int t0 = c * CHv;
    int steps = CHv;
    void* args[15];
    args[0] = (void*)&X2p;  args[1] = (void*)&hsrc; args[2] = (void*)&Khhp;
    args[3] = (void*)&Kphp; args[4] = (void*)&Kpcp; args[5] = (void*)&bPp;
    args[6] = (void*)&acp;  args[7] = (void*)&php;  args[8] = (void*)&updp;
    args[9] = (void*)&hop;  args[10] = (void*)&outp; args[11] = (void*)&hTp;
    args[12] = (void*)&ctrb; args[13] = (void*)&t0; args[14] = (void*)&steps;
    hipLaunchCooperativeKernel((const void*)qru_seq, dim3(512), dim3(256), args, 0, stream);
  }
}

// Round 5
// 7624.877 us; speedup vs baseline: 1.9531x; 1.9531x over previous
//
#include <hip/hip_runtime.h>
#include <cstddef>

#define EPSQ 1e-4f
#define S_TOT 512
#define BB 256
#define DH 256
#define NC 512
#define RR 2

// ws offsets (in floats)
#define OFF_KIH 0
#define OFF_KHH 131072
#define OFF_KPH 262144
#define OFF_KPC 393216
#define OFF_BA  524288
#define OFF_BP  524800
#define OFF_H   525312
#define OFF_X2  985088

union F4 { float4 v; float f[4]; };

// Hamilton-product component/sign tables: K[a*64+m][c*128+g] = sign[c][a]*w_{comp[c][a]}[m][g]
__constant__ int   d_comp[16] = {0,1,2,3, 1,0,3,2, 2,3,0,1, 3,2,1,0};
__constant__ float d_sign[16] = {1.f,-1.f,-1.f,-1.f, 1.f,1.f,-1.f,1.f, 1.f,1.f,1.f,-1.f, 1.f,-1.f,1.f,1.f};

// Standard row-major [k][col] layout (for K_ih, consumed by gemm_x2).
__global__ void build_qk(const float* __restrict__ wr, const float* __restrict__ wi,
                         const float* __restrict__ wj, const float* __restrict__ wk,
                         float* __restrict__ K) {
  int idx = blockIdx.x * blockDim.x + threadIdx.x;
  if (idx >= 131072) return;
  int col = idx & 511, row = idx >> 9;
  int a = row >> 6, m = row & 63;
  int c = col >> 7, g = col & 127;
  int tt = c * 4 + a;
  int cc = d_comp[tt];
  const float* s = (cc == 0) ? wr : (cc == 1) ? wi : (cc == 2) ? wj : wk;
  K[idx] = d_sign[tt] * s[m * 128 + g];
}

// k-interleaved layout: K4[(k>>2)*2048 + col*4 + (k&3)] — a float4 at
// (kb, col) holds K[4kb..4kb+3][col], so a thread's column-GEMV loads are
// perfectly coalesced float4s across consecutive-col threads.
__global__ void build_qk_i4(const float* __restrict__ wr, const float* __restrict__ wi,
                            const float* __restrict__ wj, const float* __restrict__ wk,
                            float* __restrict__ K4) {
  int idx = blockIdx.x * blockDim.x + threadIdx.x;
  if (idx >= 131072) return;
  int col = idx & 511, row = idx >> 9;   // row = k
  int a = row >> 6, m = row & 63;
  int c = col >> 7, g = col & 127;
  int tt = c * 4 + a;
  int cc = d_comp[tt];
  const float* s = (cc == 0) ? wr : (cc == 1) ? wi : (cc == 2) ? wj : wk;
  K4[(row >> 2) * 2048 + col * 4 + (row & 3)] = d_sign[tt] * s[m * 128 + g];
}

__global__ void build_bias(const float* __restrict__ b1, const float* __restrict__ b2,
                           const float* __restrict__ b3, const float* __restrict__ b4,
                           float* __restrict__ bA, float* __restrict__ bP) {
  int i = blockIdx.x * blockDim.x + threadIdx.x;
  if (i < 512) { bA[i] = b1[i] + b2[i]; bP[i] = b3[i] + b4[i]; }
}

// X2[m][n] = sum_k A[m][k]*W[k][n] + bA[n];  A:[M][256], W:[256][512]
__global__ __launch_bounds__(256) void gemm_x2(
    const float* __restrict__ A, const float* __restrict__ W,
    const float* __restrict__ bA, float* __restrict__ C) {
  __shared__ float As[16][68];
  __shared__ float Ws[16][68];
  const int tid = threadIdx.x;
  const int nt = blockIdx.x, mt = blockIdx.y;
  const int m0 = mt * 64, n0 = nt * 64;
  const int tx = tid & 15, ty = tid >> 4;
  float acc[4][4];
#pragma unroll
  for (int i = 0; i < 4; i++)
#pragma unroll
    for (int j = 0; j < 4; j++) acc[i][j] = 0.f;
  const int lr = tid >> 2, lk = (tid & 3) * 4;
  const int wkr = tid >> 4, wn = (tid & 15) * 4;
  for (int k0 = 0; k0 < 256; k0 += 16) {
    float4 a4 = *(const float4*)(A + (size_t)(m0 + lr) * 256 + k0 + lk);
    float4 w4 = *(const float4*)(W + (size_t)(k0 + wkr) * 512 + n0 + wn);
    As[lk + 0][lr] = a4.x; As[lk + 1][lr] = a4.y; As[lk + 2][lr] = a4.z; As[lk + 3][lr] = a4.w;
    *(float4*)(&Ws[wkr][wn]) = w4;
    __syncthreads();
#pragma unroll
    for (int k = 0; k < 16; k++) {
      F4 av, wv;
      av.v = *(const float4*)(&As[k][ty * 4]);
      wv.v = *(const float4*)(&Ws[k][tx * 4]);
#pragma unroll
      for (int i = 0; i < 4; i++)
#pragma unroll
        for (int j = 0; j < 4; j++) acc[i][j] += av.f[i] * wv.f[j];
    }
    __syncthreads();
  }
  F4 b4; b4.v = *(const float4*)(bA + n0 + tx * 4);
#pragma unroll
  for (int i = 0; i < 4; i++) {
    int m = m0 + ty * 4 + i;
    F4 o;
#pragma unroll
    for (int j = 0; j < 4; j++) o.f[j] = acc[i][j] + b4.f[j];
    *(float4*)(C + (size_t)m * 512 + n0 + tx * 4) = o.v;
  }
}

// State-stationary recurrent kernel: each block owns RR=2 batch rows
// end-to-end. The recurrence is row-independent, so there is NO
// inter-block communication: no barriers, no LLC exchange, no cooperative
// launch. Weights (1.5 MB total, L2-resident) are streamed every step via
// the k-interleaved layout; state (hN/cand/ac/upd) lives in LDS (12 KB).
// 128 blocks x 512 threads; thread t owns output column t.
__global__ __launch_bounds__(512, 1) void qru_rows(
    const float* __restrict__ X2,   // [steps][B][512]
    const float* __restrict__ h_in, // [B][256] raw h
    const float* __restrict__ Khh4, const float* __restrict__ Kph4,
    const float* __restrict__ Kpc4, const float* __restrict__ bP,
    float* __restrict__ h_out, float* __restrict__ out, float* __restrict__ hT,
    int steps) {
  __shared__ __align__(16) float hN[RR][256];
  __shared__ __align__(16) float cnd[RR][256];
  __shared__ __align__(16) float acL[RR][512];
  __shared__ __align__(16) float updL[RR][512];

  const int tid = threadIdx.x;
  const int row0 = blockIdx.x * RR;

  // ---- init hN = normalize(h_in) ----
  if (tid < 64 * RR) {
    const int r = tid >> 6, g = tid & 63;
    float v[4]; float ss = 0.f;
#pragma unroll
    for (int a = 0; a < 4; a++) {
      v[a] = h_in[(size_t)(row0 + r) * 256 + a * 64 + g];
      ss += v[a] * v[a];
    }
    float inv = 1.f / (sqrtf(ss) + EPSQ);
#pragma unroll
    for (int a = 0; a < 4; a++) hN[r][a * 64 + g] = v[a] * inv;
  }
  __syncthreads();

  const float* __restrict__ whh = Khh4 + tid * 4;
  const float* __restrict__ wph = Kph4 + tid * 4;
  const float* __restrict__ wpc = Kpc4 + tid * 4;
  const float bPt = bP[tid];

  for (int t = 0; t < steps; ++t) {
    // ================= P1: ac[r][t] and ph[r][t] (GEMV over K=256) =====
    float accA[RR], accU[RR];
#pragma unroll
    for (int r = 0; r < RR; r++) {
      accA[r] = X2[((size_t)t * BB + row0 + r) * 512 + tid];
      accU[r] = bPt;   // ph accumulates here; stays in register
    }
#pragma unroll 4
    for (int kb = 0; kb < 64; kb++) {
      F4 wh, wp;
      wh.v = *(const float4*)(whh + (size_t)kb * 2048);
      wp.v = *(const float4*)(wph + (size_t)kb * 2048);
#pragma unroll
      for (int r = 0; r < RR; r++) {
        F4 h4; h4.v = *(const float4*)(&hN[r][kb * 4]);   // LDS broadcast
#pragma unroll
        for (int dk = 0; dk < 4; dk++) {
          accA[r] += h4.f[dk] * wh.f[dk];
          accU[r] += h4.f[dk] * wp.f[dk];
        }
      }
    }
#pragma unroll
    for (int r = 0; r < RR; r++) acL[r][tid] = accA[r];
    __syncthreads();
    // ================= P2a: cand_t (pointwise, 128 threads) ============
    if (tid < 64 * RR) {
      const int r = tid >> 6, g = tid & 63;
      float am[4], cv[4];
#pragma unroll
      for (int a = 0; a < 4; a++) {
        am[a] = acL[r][128 * a + g];
        cv[a] = acL[r][128 * a + 64 + g];
      }
      float ag = sqrtf(am[0] * am[0] + am[1] * am[1] + am[2] * am[2] + am[3] * am[3]);
      float c0 = cv[0] * ag, c1 = cv[1] * ag, c2 = cv[2] * ag, c3 = cv[3] * ag;
      float mc = sqrtf(c0 * c0 + c1 * c1 + c2 * c2 + c3 * c3);
      float inv = 1.f / (mc + EPSQ);
      cnd[r][0 * 64 + g] = c0 * inv;
      cnd[r][1 * 64 + g] = c1 * inv;
      cnd[r][2 * 64 + g] = c2 * inv;
      cnd[r][3 * 64 + g] = c3 * inv;
    }
    __syncthreads();
    // ================= P2b: upd = ph + cand_t @ K_pc ===================
#pragma unroll 4
    for (int kb = 0; kb < 64; kb++) {
      F4 wc;
      wc.v = *(const float4*)(wpc + (size_t)kb * 2048);
#pragma unroll
      for (int r = 0; r < RR; r++) {
        F4 c4; c4.v = *(const float4*)(&cnd[r][kb * 4]);   // LDS broadcast
#pragma unroll
        for (int dk = 0; dk < 4; dk++) accU[r] += c4.f[dk] * wc.f[dk];
      }
    }
#pragma unroll
    for (int r = 0; r < RR; r++) updL[r][tid] = accU[r];
    __syncthreads();
    // ================= P3: a_new, output, renormalize ==================
    if (tid < 64 * RR) {
      const int r = tid >> 6, g = tid & 63;
      float u0 = updL[r][0 * 64 + g];
      float u1 = updL[r][1 * 64 + g];
      float u2 = updL[r][2 * 64 + g];
      float u3 = updL[r][3 * 64 + g];
      float u4 = updL[r][4 * 64 + g];
      float u5 = updL[r][5 * 64 + g];
      float u7 = updL[r][7 * 64 + g];
      float mh = sqrtf(u0 * u0 + 2.f * u2 * u2 + u4 * u4);
      float mc = sqrtf(u1 * u1 + u3 * u3 + u5 * u5 + u7 * u7);
      float av[4]; float s = 0.f;
#pragma unroll
      for (int a = 0; a < 4; a++) {
        av[a] = hN[r][a * 64 + g] * mh + cnd[r][a * 64 + g] * mc;
        s += av[a] * av[a];
      }
      float inv = 1.f / (sqrtf(s) + EPSQ);
      float* op = out + ((size_t)t * BB + row0 + r) * 256 + g;
#pragma unroll
      for (int a = 0; a < 4; a++) op[a * 64] = av[a];
      if (t == steps - 1) {
        float* hp = h_out + (size_t)(row0 + r) * 256 + g;
#pragma unroll
        for (int a = 0; a < 4; a++) hp[a * 64] = av[a];
        if (hT != nullptr) {
          float* tp = hT + (size_t)(row0 + r) * 256 + g;
#pragma unroll
          for (int a = 0; a < 4; a++) tp[a * 64] = av[a];
        }
      }
#pragma unroll
      for (int a = 0; a < 4; a++) hN[r][a * 64 + g] = av[a] * inv;
    }
    __syncthreads();
  }
}

extern "C" void kernel_launch(void* const* d_in, const int* in_sizes, int n_in,
                              void* d_out, int out_size, void* d_ws, size_t ws_size,
                              hipStream_t stream) {
  const float* input = (const float*)d_in[0];
  const float* hx = (const float*)d_in[1];
  float* ws = (float*)d_ws;
  float* Kih = ws + OFF_KIH;
  float* Khh = ws + OFF_KHH;   // interleaved
  float* Kph = ws + OFF_KPH;   // interleaved
  float* Kpc = ws + OFF_KPC;   // interleaved
  float* bA = ws + OFF_BA;
  float* bP = ws + OFF_BP;
  float* Hst = ws + OFF_H;
  float* X2b = ws + OFF_X2;

  build_qk<<<512, 256, 0, stream>>>((const float*)d_in[2], (const float*)d_in[3],
                                    (const float*)d_in[4], (const float*)d_in[5], Kih);
  build_qk_i4<<<512, 256, 0, stream>>>((const float*)d_in[6], (const float*)d_in[7],
                                       (const float*)d_in[8], (const float*)d_in[9], Khh);
  build_qk_i4<<<512, 256, 0, stream>>>((const float*)d_in[10], (const float*)d_in[11],
                                       (const float*)d_in[12], (const float*)d_in[13], Kpc);
  build_qk_i4<<<512, 256, 0, stream>>>((const float*)d_in[14], (const float*)d_in[15],
                                       (const float*)d_in[16], (const float*)d_in[17], Kph);
  build_bias<<<2, 256, 0, stream>>>((const float*)d_in[18], (const float*)d_in[19],
                                    (const float*)d_in[20], (const float*)d_in[21], bA, bP);

  // pick largest chunk of steps whose X2 buffer fits in ws
  int CHv = 64;
  while (CHv > 8 && ((size_t)OFF_X2 + (size_t)CHv * BB * NC) * 4 > ws_size) CHv >>= 1;
  const int nch = S_TOT / CHv;

  for (int c = 0; c < nch; ++c) {
    gemm_x2<<<dim3(8, CHv * 4), 256, 0, stream>>>(
        input + (size_t)c * CHv * BB * DH, Kih, bA, X2b);

    const float* hsrc = (c == 0) ? hx : (const float*)Hst;
    float* outp = (float*)d_out + (size_t)c * CHv * BB * DH;
    float* hTp = (c == nch - 1) ? ((float*)d_out + (size_t)S_TOT * BB * DH) : nullptr;
    qru_rows<<<dim3(BB / RR), dim3(512), 0, stream>>>(
        X2b, hsrc, Khh, Kph, Kpc, bP, Hst, outp, hTp, CHv);
  }
}

// Round 6
// 6763.090 us; speedup vs baseline: 2.2019x; 1.1274x over previous
//
#include <hip/hip_runtime.h>
#include <cstddef>

#define EPSQ 1e-4f
#define S_TOT 512
#define BB 256
#define DH 256
#define NC 512
#define RR 2

// ws offsets (in floats)
#define OFF_KIH 0
#define OFF_BHH 131072
#define OFF_BPH 163840
#define OFF_BPC 196608
#define OFF_BA  229376
#define OFF_BP  229888
#define OFF_H   230400
#define OFF_X2  295936

union F4 { float4 v; float f[4]; };

// Hamilton-product tables: K[a*64+m][c*128+g] = QS[c*4+a]*w_{QC[c*4+a]}[m][g]
static constexpr int   QC[16] = {0,1,2,3, 1,0,3,2, 2,3,0,1, 3,2,1,0};
static constexpr float QS[16] = {1.f,-1.f,-1.f,-1.f, 1.f,1.f,-1.f,1.f,
                                 1.f,1.f,1.f,-1.f, 1.f,-1.f,1.f,1.f};
__constant__ int   d_comp[16] = {0,1,2,3, 1,0,3,2, 2,3,0,1, 3,2,1,0};
__constant__ float d_sign[16] = {1.f,-1.f,-1.f,-1.f, 1.f,1.f,-1.f,1.f, 1.f,1.f,1.f,-1.f, 1.f,-1.f,1.f,1.f};

// Expanded row-major [k][col] layout (K_ih only, consumed by gemm_x2).
__global__ void build_qk(const float* __restrict__ wr, const float* __restrict__ wi,
                         const float* __restrict__ wj, const float* __restrict__ wk,
                         float* __restrict__ K) {
  int idx = blockIdx.x * blockDim.x + threadIdx.x;
  if (idx >= 131072) return;
  int col = idx & 511, row = idx >> 9;
  int a = row >> 6, m = row & 63;
  int c = col >> 7, g = col & 127;
  int tt = c * 4 + a;
  int cc = d_comp[tt];
  const float* s = (cc == 0) ? wr : (cc == 1) ? wi : (cc == 2) ? wj : wk;
  K[idx] = d_sign[tt] * s[m * 128 + g];
}

// Base-matrix m-interleaved layout: B4[x*8192 + (m>>2)*512 + g*4 + (m&3)]
// = w_x[m][g]; a float4 at (mb, g) holds w_x[4mb..4mb+3][g]. 32 KB per
// component, 128 KB per set (4x smaller than the expanded K).
__global__ void build_base(const float* __restrict__ wr, const float* __restrict__ wi,
                           const float* __restrict__ wj, const float* __restrict__ wk,
                           float* __restrict__ B4) {
  int idx = blockIdx.x * blockDim.x + threadIdx.x;
  if (idx >= 32768) return;
  int x = idx >> 13;
  int rem = idx & 8191;          // m*128 + g
  int m = rem >> 7, g = rem & 127;
  const float* s = (x == 0) ? wr : (x == 1) ? wi : (x == 2) ? wj : wk;
  B4[x * 8192 + (m >> 2) * 512 + g * 4 + (m & 3)] = s[rem];
}

__global__ void build_bias(const float* __restrict__ b1, const float* __restrict__ b2,
                           const float* __restrict__ b3, const float* __restrict__ b4,
                           float* __restrict__ bA, float* __restrict__ bP) {
  int i = blockIdx.x * blockDim.x + threadIdx.x;
  if (i < 512) { bA[i] = b1[i] + b2[i]; bP[i] = b3[i] + b4[i]; }
}

// X2[m][n] = sum_k A[m][k]*W[k][n] + bA[n];  A:[M][256], W:[256][512]
__global__ __launch_bounds__(256) void gemm_x2(
    const float* __restrict__ A, const float* __restrict__ W,
    const float* __restrict__ bA, float* __restrict__ C) {
  __shared__ float As[16][68];
  __shared__ float Ws[16][68];
  const int tid = threadIdx.x;
  const int nt = blockIdx.x, mt = blockIdx.y;
  const int m0 = mt * 64, n0 = nt * 64;
  const int tx = tid & 15, ty = tid >> 4;
  float acc[4][4];
#pragma unroll
  for (int i = 0; i < 4; i++)
#pragma unroll
    for (int j = 0; j < 4; j++) acc[i][j] = 0.f;
  const int lr = tid >> 2, lk = (tid & 3) * 4;
  const int wkr = tid >> 4, wn = (tid & 15) * 4;
  for (int k0 = 0; k0 < 256; k0 += 16) {
    float4 a4 = *(const float4*)(A + (size_t)(m0 + lr) * 256 + k0 + lk);
    float4 w4 = *(const float4*)(W + (size_t)(k0 + wkr) * 512 + n0 + wn);
    As[lk + 0][lr] = a4.x; As[lk + 1][lr] = a4.y; As[lk + 2][lr] = a4.z; As[lk + 3][lr] = a4.w;
    *(float4*)(&Ws[wkr][wn]) = w4;
    __syncthreads();
#pragma unroll
    for (int k = 0; k < 16; k++) {
      F4 av, wv;
      av.v = *(const float4*)(&As[k][ty * 4]);
      wv.v = *(const float4*)(&Ws[k][tx * 4]);
#pragma unroll
      for (int i = 0; i < 4; i++)
#pragma unroll
        for (int j = 0; j < 4; j++) acc[i][j] += av.f[i] * wv.f[j];
    }
    __syncthreads();
  }
  F4 b4; b4.v = *(const float4*)(bA + n0 + tx * 4);
#pragma unroll
  for (int i = 0; i < 4; i++) {
    int m = m0 + ty * 4 + i;
    F4 o;
#pragma unroll
    for (int j = 0; j < 4; j++) o.f[j] = acc[i][j] + b4.f[j];
    *(float4*)(C + (size_t)m * 512 + n0 + tx * 4) = o.v;
  }
}

// State-stationary recurrent kernel, base-weight streaming.
// 128 blocks x 1024 threads; block owns RR=2 batch rows end-to-end, no
// inter-block communication. Per step each block streams only the BASE
// quaternion matrices (3 x 128 KB) and reconstructs the Hamilton products
// in-register via D[a][x] = sum_m hN[a*64+m]*w_x[m][g] and compile-time
// sign/component tables. Every base element is loaded exactly once per
// block per step (P1: mat x kq 4-way m-split; P2b: 8-way m-split).
__global__ __launch_bounds__(1024, 1) void qru_rows(
    const float* __restrict__ X2,   // [steps][B][512]
    const float* __restrict__ h_in, // [B][256] raw h
    const float* __restrict__ Bhh, const float* __restrict__ Bph,
    const float* __restrict__ Bpc, const float* __restrict__ bP,
    float* __restrict__ h_out, float* __restrict__ out, float* __restrict__ hT,
    int steps) {
  __shared__ __align__(16) float hN[RR][256];
  __shared__ __align__(16) float cnd[RR][256];
  __shared__ __align__(16) float acL[RR][512];
  __shared__ __align__(16) float updL[RR][512];
  __shared__ __align__(16) float pac[8192];  // partial scratch, 32 KB

  const int tid = threadIdx.x;
  const int row0 = blockIdx.x * RR;

  // partial-role bits (P1): mat(2) x kq(4) x g(128), rows folded in-thread
  const int mat = tid >> 9;
  const int kq  = (tid >> 7) & 3;
  const int g   = tid & 127;
  // finalize-role bits: mat(2) x fr(row,2) x fs(c-pair,2) x g(128)
  const int fr  = (tid >> 8) & 1;
  const int fs  = (tid >> 7) & 1;
  // P2b partial-role bits: k8(8) x g(128), rows folded in-thread
  const int k8  = tid >> 7;

  const float* Wp1 = ((mat == 0) ? Bhh : Bph) + (size_t)(kq * 4) * 512 + (size_t)g * 4;
  const float* Wcc = Bpc + (size_t)(k8 * 2) * 512 + (size_t)g * 4;

  // bias for the ph/upd path (finalize role, constant over t)
  float bpv[2] = { bP[(fs * 2 + 0) * 128 + g], bP[(fs * 2 + 1) * 128 + g] };

  // ---- init hN = normalize(h_in) ----
  if (tid < 64 * RR) {
    const int r = tid >> 6, gg = tid & 63;
    float v[4]; float ss = 0.f;
#pragma unroll
    for (int a = 0; a < 4; a++) {
      v[a] = h_in[(size_t)(row0 + r) * 256 + a * 64 + gg];
      ss += v[a] * v[a];
    }
    float inv = 1.f / (sqrtf(ss) + EPSQ);
#pragma unroll
    for (int a = 0; a < 4; a++) hN[r][a * 64 + gg] = v[a] * inv;
  }
  __syncthreads();

  for (int t = 0; t < steps; ++t) {
    // prefetch X2 additive term (finalize role, hidden under P1 FMAs)
    float x2v[2] = {0.f, 0.f};
    if (mat == 0) {
#pragma unroll
      for (int cc = 0; cc < 2; cc++)
        x2v[cc] = X2[((size_t)t * BB + row0 + fr) * 512 + (fs * 2 + cc) * 128 + g];
    }
    // ================= P1 partial: D[r][a][x] over m in [kq*16, kq*16+16)
    {
      float D[RR][4][4] = {};
#pragma unroll
      for (int mb = 0; mb < 4; mb++) {
        F4 w[4];
#pragma unroll
        for (int x = 0; x < 4; x++)
          w[x].v = *(const float4*)(Wp1 + (size_t)x * 8192 + mb * 512);
#pragma unroll
        for (int r = 0; r < RR; r++)
#pragma unroll
          for (int a = 0; a < 4; a++) {
            F4 h4; h4.v = *(const float4*)(&hN[r][a * 64 + kq * 16 + mb * 4]);
#pragma unroll
            for (int x = 0; x < 4; x++)
#pragma unroll
              for (int dk = 0; dk < 4; dk++)
                D[r][a][x] += h4.f[dk] * w[x].f[dk];
          }
      }
      // sign/component combine -> partial outputs for 4 c's per row
#pragma unroll
      for (int r = 0; r < RR; r++)
#pragma unroll
        for (int c = 0; c < 4; c++) {
          float o = 0.f;
#pragma unroll
          for (int a = 0; a < 4; a++) {
            const int tt = c * 4 + a;
            o += QS[tt] * D[r][a][QC[tt]];
          }
          pac[(((((mat * 4 + kq) * 2 + r) * 4) + c) << 7) + g] = o;
        }
    }
    __syncthreads();
    // ================= P1 finalize: ac -> LDS, ph -> registers ========
    float phv[2];
#pragma unroll
    for (int cc = 0; cc < 2; cc++) {
      const int c = fs * 2 + cc;
      float s = 0.f;
#pragma unroll
      for (int q = 0; q < 4; q++)
        s += pac[(((((mat * 4 + q) * 2 + fr) * 4) + c) << 7) + g];
      if (mat == 0) acL[fr][c * 128 + g] = s + x2v[cc];
      else phv[cc] = s + bpv[cc];
    }
    __syncthreads();
    // ================= P2a: cand_t (pointwise, 128 threads) ===========
    if (tid < 64 * RR) {
      const int r = tid >> 6, gg = tid & 63;
      float am[4], cv[4];
#pragma unroll
      for (int a = 0; a < 4; a++) {
        am[a] = acL[r][128 * a + gg];
        cv[a] = acL[r][128 * a + 64 + gg];
      }
      float ag = sqrtf(am[0] * am[0] + am[1] * am[1] + am[2] * am[2] + am[3] * am[3]);
      float c0 = cv[0] * ag, c1 = cv[1] * ag, c2 = cv[2] * ag, c3 = cv[3] * ag;
      float mc = sqrtf(c0 * c0 + c1 * c1 + c2 * c2 + c3 * c3);
      float inv = 1.f / (mc + EPSQ);
      cnd[r][0 * 64 + gg] = c0 * inv;
      cnd[r][1 * 64 + gg] = c1 * inv;
      cnd[r][2 * 64 + gg] = c2 * inv;
      cnd[r][3 * 64 + gg] = c3 * inv;
    }
    __syncthreads();
    // ================= P2b partial: upd GEMV, 8-way m-split ===========
    {
      float E[RR][4][4] = {};
#pragma unroll
      for (int mb = 0; mb < 2; mb++) {
        F4 w[4];
#pragma unroll
        for (int x = 0; x < 4; x++)
          w[x].v = *(const float4*)(Wcc + (size_t)x * 8192 + mb * 512);
#pragma unroll
        for (int r = 0; r < RR; r++)
#pragma unroll
          for (int a = 0; a < 4; a++) {
            F4 c4; c4.v = *(const float4*)(&cnd[r][a * 64 + k8 * 8 + mb * 4]);
#pragma unroll
            for (int x = 0; x < 4; x++)
#pragma unroll
              for (int dk = 0; dk < 4; dk++)
                E[r][a][x] += c4.f[dk] * w[x].f[dk];
          }
      }
#pragma unroll
      for (int r = 0; r < RR; r++)
#pragma unroll
        for (int c = 0; c < 4; c++) {
          float o = 0.f;
#pragma unroll
          for (int a = 0; a < 4; a++) {
            const int tt = c * 4 + a;
            o += QS[tt] * E[r][a][QC[tt]];
          }
          pac[((((k8 * 2 + r) * 4) + c) << 7) + g] = o;
        }
    }
    __syncthreads();
    // ================= P2b finalize (mat==1 threads): upd -> LDS ======
    if (mat == 1) {
#pragma unroll
      for (int cc = 0; cc < 2; cc++) {
        const int c = fs * 2 + cc;
        float s = phv[cc];
#pragma unroll
        for (int q = 0; q < 8; q++)
          s += pac[((((q * 2 + fr) * 4) + c) << 7) + g];
        updL[fr][c * 128 + g] = s;
      }
    }
    __syncthreads();
    // ================= P3: a_new, output, renormalize =================
    if (tid < 64 * RR) {
      const int r = tid >> 6, gg = tid & 63;
      float u0 = updL[r][0 * 64 + gg];
      float u1 = updL[r][1 * 64 + gg];
      float u2 = updL[r][2 * 64 + gg];
      float u3 = updL[r][3 * 64 + gg];
      float u4 = updL[r][4 * 64 + gg];
      float u5 = updL[r][5 * 64 + gg];
      float u7 = updL[r][7 * 64 + gg];
      float mh = sqrtf(u0 * u0 + 2.f * u2 * u2 + u4 * u4);
      float mc = sqrtf(u1 * u1 + u3 * u3 + u5 * u5 + u7 * u7);
      float av[4]; float s = 0.f;
#pragma unroll
      for (int a = 0; a < 4; a++) {
        av[a] = hN[r][a * 64 + gg] * mh + cnd[r][a * 64 + gg] * mc;
        s += av[a] * av[a];
      }
      float inv = 1.f / (sqrtf(s) + EPSQ);
      float* op = out + ((size_t)t * BB + row0 + r) * 256 + gg;
#pragma unroll
      for (int a = 0; a < 4; a++) op[a * 64] = av[a];
      if (t == steps - 1) {
        float* hp = h_out + (size_t)(row0 + r) * 256 + gg;
#pragma unroll
        for (int a = 0; a < 4; a++) hp[a * 64] = av[a];
        if (hT != nullptr) {
          float* tp = hT + (size_t)(row0 + r) * 256 + gg;
#pragma unroll
          for (int a = 0; a < 4; a++) tp[a * 64] = av[a];
        }
      }
#pragma unroll
      for (int a = 0; a < 4; a++) hN[r][a * 64 + gg] = av[a] * inv;
    }
    __syncthreads();
  }
}

extern "C" void kernel_launch(void* const* d_in, const int* in_sizes, int n_in,
                              void* d_out, int out_size, void* d_ws, size_t ws_size,
                              hipStream_t stream) {
  const float* input = (const float*)d_in[0];
  const float* hx = (const float*)d_in[1];
  float* ws = (float*)d_ws;
  float* Kih = ws + OFF_KIH;
  float* Bhh = ws + OFF_BHH;
  float* Bph = ws + OFF_BPH;
  float* Bpc = ws + OFF_BPC;
  float* bA = ws + OFF_BA;
  float* bP = ws + OFF_BP;
  float* Hst = ws + OFF_H;
  float* X2b = ws + OFF_X2;

  build_qk<<<512, 256, 0, stream>>>((const float*)d_in[2], (const float*)d_in[3],
                                    (const float*)d_in[4], (const float*)d_in[5], Kih);
  build_base<<<128, 256, 0, stream>>>((const float*)d_in[6], (const float*)d_in[7],
                                      (const float*)d_in[8], (const float*)d_in[9], Bhh);
  build_base<<<128, 256, 0, stream>>>((const float*)d_in[10], (const float*)d_in[11],
                                      (const float*)d_in[12], (const float*)d_in[13], Bpc);
  build_base<<<128, 256, 0, stream>>>((const float*)d_in[14], (const float*)d_in[15],
                                      (const float*)d_in[16], (const float*)d_in[17], Bph);
  build_bias<<<2, 256, 0, stream>>>((const float*)d_in[18], (const float*)d_in[19],
                                    (const float*)d_in[20], (const float*)d_in[21], bA, bP);

  // pick largest chunk of steps whose X2 buffer fits in ws
  int CHv = 64;
  while (CHv > 8 && ((size_t)OFF_X2 + (size_t)CHv * BB * NC) * 4 > ws_size) CHv >>= 1;
  const int nch = S_TOT / CHv;

  for (int c = 0; c < nch; ++c) {
    gemm_x2<<<dim3(8, CHv * 4), 256, 0, stream>>>(
        input + (size_t)c * CHv * BB * DH, Kih, bA, X2b);

    const float* hsrc = (c == 0) ? hx : (const float*)Hst;
    float* outp = (float*)d_out + (size_t)c * CHv * BB * DH;
    float* hTp = (c == nch - 1) ? ((float*)d_out + (size_t)S_TOT * BB * DH) : nullptr;
    qru_rows<<<dim3(BB / RR), dim3(1024), 0, stream>>>(
        X2b, hsrc, Bhh, Bph, Bpc, bP, Hst, outp, hTp, CHv);
  }
}

// Round 7
// 4715.094 us; speedup vs baseline: 3.1583x; 1.4343x over previous
//
#include <hip/hip_runtime.h>
#include <cstddef>

#define EPSQ 1e-4f
#define S_TOT 512
#define BB 256
#define DH 256
#define NC 512

// ws offsets (in floats)
#define OFF_KIH 0
#define OFF_BHH 131072
#define OFF_BPH 163840
#define OFF_BPC 196608
#define OFF_BA  229376
#define OFF_BP  229888
#define OFF_H   230400
#define OFF_X2  295936

union F4 { float4 v; float f[4]; };

// Hamilton-product tables: K[a*64+m][c*128+g] = QS[c*4+a]*w_{QC[c*4+a]}[m][g]
static constexpr int   QC[16] = {0,1,2,3, 1,0,3,2, 2,3,0,1, 3,2,1,0};
static constexpr float QS[16] = {1.f,-1.f,-1.f,-1.f, 1.f,1.f,-1.f,1.f,
                                 1.f,1.f,1.f,-1.f, 1.f,-1.f,1.f,1.f};
__constant__ int   d_comp[16] = {0,1,2,3, 1,0,3,2, 2,3,0,1, 3,2,1,0};
__constant__ float d_sign[16] = {1.f,-1.f,-1.f,-1.f, 1.f,1.f,-1.f,1.f, 1.f,1.f,1.f,-1.f, 1.f,-1.f,1.f,1.f};

// Expanded row-major [k][col] layout (K_ih only, consumed by gemm_x2).
__global__ void build_qk(const float* __restrict__ wr, const float* __restrict__ wi,
                         const float* __restrict__ wj, const float* __restrict__ wk,
                         float* __restrict__ K) {
  int idx = blockIdx.x * blockDim.x + threadIdx.x;
  if (idx >= 131072) return;
  int col = idx & 511, row = idx >> 9;
  int a = row >> 6, m = row & 63;
  int c = col >> 7, g = col & 127;
  int tt = c * 4 + a;
  int cc = d_comp[tt];
  const float* s = (cc == 0) ? wr : (cc == 1) ? wi : (cc == 2) ? wj : wk;
  K[idx] = d_sign[tt] * s[m * 128 + g];
}

// Base-matrix m-interleaved layout: B4[x*8192 + (m>>2)*512 + g*4 + (m&3)]
// = w_x[m][g]; a float4 at (mb, g) holds w_x[4mb..4mb+3][g]. 32 KB per
// component, 128 KB per set (4x smaller than the expanded K).
__global__ void build_base(const float* __restrict__ wr, const float* __restrict__ wi,
                           const float* __restrict__ wj, const float* __restrict__ wk,
                           float* __restrict__ B4) {
  int idx = blockIdx.x * blockDim.x + threadIdx.x;
  if (idx >= 32768) return;
  int x = idx >> 13;
  int rem = idx & 8191;          // m*128 + g
  int m = rem >> 7, g = rem & 127;
  const float* s = (x == 0) ? wr : (x == 1) ? wi : (x == 2) ? wj : wk;
  B4[x * 8192 + (m >> 2) * 512 + g * 4 + (m & 3)] = s[rem];
}

__global__ void build_bias(const float* __restrict__ b1, const float* __restrict__ b2,
                           const float* __restrict__ b3, const float* __restrict__ b4,
                           float* __restrict__ bA, float* __restrict__ bP) {
  int i = blockIdx.x * blockDim.x + threadIdx.x;
  if (i < 512) { bA[i] = b1[i] + b2[i]; bP[i] = b3[i] + b4[i]; }
}

// X2[m][n] = sum_k A[m][k]*W[k][n] + bA[n];  A:[M][256], W:[256][512]
__global__ __launch_bounds__(256) void gemm_x2(
    const float* __restrict__ A, const float* __restrict__ W,
    const float* __restrict__ bA, float* __restrict__ C) {
  __shared__ float As[16][68];
  __shared__ float Ws[16][68];
  const int tid = threadIdx.x;
  const int nt = blockIdx.x, mt = blockIdx.y;
  const int m0 = mt * 64, n0 = nt * 64;
  const int tx = tid & 15, ty = tid >> 4;
  float acc[4][4];
#pragma unroll
  for (int i = 0; i < 4; i++)
#pragma unroll
    for (int j = 0; j < 4; j++) acc[i][j] = 0.f;
  const int lr = tid >> 2, lk = (tid & 3) * 4;
  const int wkr = tid >> 4, wn = (tid & 15) * 4;
  for (int k0 = 0; k0 < 256; k0 += 16) {
    float4 a4 = *(const float4*)(A + (size_t)(m0 + lr) * 256 + k0 + lk);
    float4 w4 = *(const float4*)(W + (size_t)(k0 + wkr) * 512 + n0 + wn);
    As[lk + 0][lr] = a4.x; As[lk + 1][lr] = a4.y; As[lk + 2][lr] = a4.z; As[lk + 3][lr] = a4.w;
    *(float4*)(&Ws[wkr][wn]) = w4;
    __syncthreads();
#pragma unroll
    for (int k = 0; k < 16; k++) {
      F4 av, wv;
      av.v = *(const float4*)(&As[k][ty * 4]);
      wv.v = *(const float4*)(&Ws[k][tx * 4]);
#pragma unroll
      for (int i = 0; i < 4; i++)
#pragma unroll
        for (int j = 0; j < 4; j++) acc[i][j] += av.f[i] * wv.f[j];
    }
    __syncthreads();
  }
  F4 b4; b4.v = *(const float4*)(bA + n0 + tx * 4);
#pragma unroll
  for (int i = 0; i < 4; i++) {
    int m = m0 + ty * 4 + i;
    F4 o;
#pragma unroll
    for (int j = 0; j < 4; j++) o.f[j] = acc[i][j] + b4.f[j];
    *(float4*)(C + (size_t)m * 512 + n0 + tx * 4) = o.v;
  }
}

// State-stationary recurrent kernel, base-weight streaming, fused
// sign-combine (no D-array => no spills). 256 blocks x 512 threads; each
// block owns ONE batch row end-to-end: no inter-block communication.
// Per step each block streams the base quaternion matrices (3 x 128 KB,
// L2-resident) exactly once; Hamilton expansion is folded into the FMA
// signs via compile-time QS/QC tables. State lives in 16 KB LDS.
__global__ __launch_bounds__(512, 2) void qru_rows(
    const float* __restrict__ X2,   // [steps][B][512]
    const float* __restrict__ h_in, // [B][256] raw h
    const float* __restrict__ Bhh, const float* __restrict__ Bph,
    const float* __restrict__ Bpc, const float* __restrict__ bP,
    float* __restrict__ h_out, float* __restrict__ out, float* __restrict__ hT,
    int steps) {
  __shared__ __align__(16) float hN[256];
  __shared__ __align__(16) float cnd[256];
  __shared__ __align__(16) float acL[512];
  __shared__ __align__(16) float phL[512];
  __shared__ __align__(16) float updL[512];
  __shared__ __align__(16) float pac[2048];   // partial scratch, 8 KB

  const int tid = threadIdx.x;
  const int row = blockIdx.x;
  const int g   = tid & 127;
  const int hi  = tid >> 7;          // 0..3
  // P1 partial roles: mat(2) x kq(2); P2b partial roles: k8 = hi
  const int mat = hi >> 1;
  const int kq  = hi & 1;
  // finalize roles: fm(2) x fc2(2)
  const int fm  = hi >> 1;
  const int fc2 = hi & 1;

  const float* Wp1 = ((mat == 0) ? Bhh : Bph) + (size_t)kq * 4096 + (size_t)g * 4;
  const float* Wcc = Bpc + (size_t)hi * 2048 + (size_t)g * 4;

  // biases for the finalize role (constant over t)
  float bpv[2] = { bP[(fc2 * 2 + 0) * 128 + g], bP[(fc2 * 2 + 1) * 128 + g] };

  // ---- init hN = normalize(h_in) ----
  if (tid < 64) {
    float v[4]; float ss = 0.f;
#pragma unroll
    for (int a = 0; a < 4; a++) {
      v[a] = h_in[(size_t)row * 256 + a * 64 + tid];
      ss += v[a] * v[a];
    }
    float inv = 1.f / (sqrtf(ss) + EPSQ);
#pragma unroll
    for (int a = 0; a < 4; a++) hN[a * 64 + tid] = v[a] * inv;
  }
  __syncthreads();

  for (int t = 0; t < steps; ++t) {
    // prefetch X2 additive term (fm==0 finalize threads); overlaps P1 FMAs
    float x2v[2] = {0.f, 0.f};
    if (fm == 0) {
#pragma unroll
      for (int cc = 0; cc < 2; cc++)
        x2v[cc] = X2[((size_t)t * BB + row) * 512 + (fc2 * 2 + cc) * 128 + g];
    }
    // ===== P1 partial: this thread's mat over m in [kq*32, kq*32+32) ====
    {
      float o[4] = {0.f, 0.f, 0.f, 0.f};
#pragma unroll 2
      for (int mb = 0; mb < 8; mb++) {
        F4 w[4];
#pragma unroll
        for (int x = 0; x < 4; x++)
          w[x].v = *(const float4*)(Wp1 + (size_t)x * 8192 + mb * 512);
#pragma unroll
        for (int a = 0; a < 4; a++) {
          F4 h4; h4.v = *(const float4*)(&hN[a * 64 + kq * 32 + mb * 4]);
#pragma unroll
          for (int dk = 0; dk < 4; dk++)
#pragma unroll
            for (int c = 0; c < 4; c++) {
              const int tt = c * 4 + a;
              o[c] += QS[tt] * h4.f[dk] * w[QC[tt]].f[dk];
            }
        }
      }
#pragma unroll
      for (int c = 0; c < 4; c++) pac[(hi * 4 + c) * 128 + g] = o[c];
    }
    __syncthreads();
    // ===== P1 finalize: ac -> acL (+X2), ph -> phL (+bias) ==============
    {
#pragma unroll
      for (int cc = 0; cc < 2; cc++) {
        const int c = fc2 * 2 + cc;
        float s = pac[((fm * 2 + 0) * 4 + c) * 128 + g]
                + pac[((fm * 2 + 1) * 4 + c) * 128 + g];
        if (fm == 0) acL[c * 128 + g] = s + x2v[cc];
        else         phL[c * 128 + g] = s + bpv[cc];
      }
    }
    __syncthreads();
    // ===== P2a: cand_t (pointwise, 64 threads) ==========================
    if (tid < 64) {
      float am[4], cv[4];
#pragma unroll
      for (int a = 0; a < 4; a++) {
        am[a] = acL[a * 128 + tid];
        cv[a] = acL[a * 128 + 64 + tid];
      }
      float ag = sqrtf(am[0] * am[0] + am[1] * am[1] + am[2] * am[2] + am[3] * am[3]);
      float c0 = cv[0] * ag, c1 = cv[1] * ag, c2 = cv[2] * ag, c3 = cv[3] * ag;
      float mc = sqrtf(c0 * c0 + c1 * c1 + c2 * c2 + c3 * c3);
      float inv = 1.f / (mc + EPSQ);
      cnd[0 * 64 + tid] = c0 * inv;
      cnd[1 * 64 + tid] = c1 * inv;
      cnd[2 * 64 + tid] = c2 * inv;
      cnd[3 * 64 + tid] = c3 * inv;
    }
    __syncthreads();
    // ===== P2b partial: upd GEMV, m in [hi*16, hi*16+16) ================
    {
      float o[4] = {0.f, 0.f, 0.f, 0.f};
#pragma unroll 2
      for (int mb = 0; mb < 4; mb++) {
        F4 w[4];
#pragma unroll
        for (int x = 0; x < 4; x++)
          w[x].v = *(const float4*)(Wcc + (size_t)x * 8192 + mb * 512);
#pragma unroll
        for (int a = 0; a < 4; a++) {
          F4 c4; c4.v = *(const float4*)(&cnd[a * 64 + hi * 16 + mb * 4]);
#pragma unroll
          for (int dk = 0; dk < 4; dk++)
#pragma unroll
            for (int c = 0; c < 4; c++) {
              const int tt = c * 4 + a;
              o[c] += QS[tt] * c4.f[dk] * w[QC[tt]].f[dk];
            }
        }
      }
#pragma unroll
      for (int c = 0; c < 4; c++) pac[(hi * 4 + c) * 128 + g] = o[c];
    }
    __syncthreads();
    // ===== P2b finalize: updL = phL + sum of 4 partials =================
    {
      float s = phL[hi * 128 + g];
#pragma unroll
      for (int k8 = 0; k8 < 4; k8++) s += pac[(k8 * 4 + hi) * 128 + g];
      updL[hi * 128 + g] = s;
    }
    __syncthreads();
    // ===== P3: a_new, output, renormalize (64 threads) ==================
    if (tid < 64) {
      float u0 = updL[0 * 64 + tid];
      float u1 = updL[1 * 64 + tid];
      float u2 = updL[2 * 64 + tid];
      float u3 = updL[3 * 64 + tid];
      float u4 = updL[4 * 64 + tid];
      float u5 = updL[5 * 64 + tid];
      float u7 = updL[7 * 64 + tid];
      float mh = sqrtf(u0 * u0 + 2.f * u2 * u2 + u4 * u4);
      float mc = sqrtf(u1 * u1 + u3 * u3 + u5 * u5 + u7 * u7);
      float av[4]; float s = 0.f;
#pragma unroll
      for (int a = 0; a < 4; a++) {
        av[a] = hN[a * 64 + tid] * mh + cnd[a * 64 + tid] * mc;
        s += av[a] * av[a];
      }
      float inv = 1.f / (sqrtf(s) + EPSQ);
      float* op = out + ((size_t)t * BB + row) * 256 + tid;
#pragma unroll
      for (int a = 0; a < 4; a++) op[a * 64] = av[a];
      if (t == steps - 1) {
        float* hp = h_out + (size_t)row * 256 + tid;
#pragma unroll
        for (int a = 0; a < 4; a++) hp[a * 64] = av[a];
        if (hT != nullptr) {
          float* tp = hT + (size_t)row * 256 + tid;
#pragma unroll
          for (int a = 0; a < 4; a++) tp[a * 64] = av[a];
        }
      }
#pragma unroll
      for (int a = 0; a < 4; a++) hN[a * 64 + tid] = av[a] * inv;
    }
    __syncthreads();
  }
}

extern "C" void kernel_launch(void* const* d_in, const int* in_sizes, int n_in,
                              void* d_out, int out_size, void* d_ws, size_t ws_size,
                              hipStream_t stream) {
  const float* input = (const float*)d_in[0];
  const float* hx = (const float*)d_in[1];
  float* ws = (float*)d_ws;
  float* Kih = ws + OFF_KIH;
  float* Bhh = ws + OFF_BHH;
  float* Bph = ws + OFF_BPH;
  float* Bpc = ws + OFF_BPC;
  float* bA = ws + OFF_BA;
  float* bP = ws + OFF_BP;
  float* Hst = ws + OFF_H;
  float* X2b = ws + OFF_X2;

  build_qk<<<512, 256, 0, stream>>>((const float*)d_in[2], (const float*)d_in[3],
                                    (const float*)d_in[4], (const float*)d_in[5], Kih);
  build_base<<<128, 256, 0, stream>>>((const float*)d_in[6], (const float*)d_in[7],
                                      (const float*)d_in[8], (const float*)d_in[9], Bhh);
  build_base<<<128, 256, 0, stream>>>((const float*)d_in[10], (const float*)d_in[11],
                                      (const float*)d_in[12], (const float*)d_in[13], Bpc);
  build_base<<<128, 256, 0, stream>>>((const float*)d_in[14], (const float*)d_in[15],
                                      (const float*)d_in[16], (const float*)d_in[17], Bph);
  build_bias<<<2, 256, 0, stream>>>((const float*)d_in[18], (const float*)d_in[19],
                                    (const float*)d_in[20], (const float*)d_in[21], bA, bP);

  // pick largest chunk of steps whose X2 buffer fits in ws
  int CHv = 64;
  while (CHv > 8 && ((size_t)OFF_X2 + (size_t)CHv * BB * NC) * 4 > ws_size) CHv >>= 1;
  const int nch = S_TOT / CHv;

  for (int c = 0; c < nch; ++c) {
    gemm_x2<<<dim3(8, CHv * 4), 256, 0, stream>>>(
        input + (size_t)c * CHv * BB * DH, Kih, bA, X2b);

    const float* hsrc = (c == 0) ? hx : (const float*)Hst;
    float* outp = (float*)d_out + (size_t)c * CHv * BB * DH;
    float* hTp = (c == nch - 1) ? ((float*)d_out + (size_t)S_TOT * BB * DH) : nullptr;
    qru_rows<<<dim3(BB), dim3(512), 0, stream>>>(
        X2b, hsrc, Bhh, Bph, Bpc, bP, Hst, outp, hTp, CHv);
  }
}

// Round 8
// 2480.853 us; speedup vs baseline: 6.0027x; 1.9006x over previous
//
#include <hip/hip_runtime.h>
#include <cstddef>

#define EPSQ 1e-4f
#define S_TOT 512
#define BB 256
#define DH 256
#define NC 512

// ws offsets (in floats)
#define OFF_KIH 0
#define OFF_BHH 131072
#define OFF_BPH 163840
#define OFF_BPC 196608
#define OFF_BA  229376
#define OFF_BP  229888
#define OFF_H   230400
#define OFF_X2  295936

union F4 { float4 v; float f[4]; };

__constant__ int   d_comp[16] = {0,1,2,3, 1,0,3,2, 2,3,0,1, 3,2,1,0};
__constant__ float d_sign[16] = {1.f,-1.f,-1.f,-1.f, 1.f,1.f,-1.f,1.f, 1.f,1.f,1.f,-1.f, 1.f,-1.f,1.f,1.f};

// Expanded row-major [k][col] layout (K_ih only, consumed by gemm_x2).
__global__ void build_qk(const float* __restrict__ wr, const float* __restrict__ wi,
                         const float* __restrict__ wj, const float* __restrict__ wk,
                         float* __restrict__ K) {
  int idx = blockIdx.x * blockDim.x + threadIdx.x;
  if (idx >= 131072) return;
  int col = idx & 511, row = idx >> 9;
  int a = row >> 6, m = row & 63;
  int c = col >> 7, g = col & 127;
  int tt = c * 4 + a;
  int cc = d_comp[tt];
  const float* s = (cc == 0) ? wr : (cc == 1) ? wi : (cc == 2) ? wj : wk;
  K[idx] = d_sign[tt] * s[m * 128 + g];
}

// Base-matrix m-interleaved layout: B4[x*8192 + (m>>2)*512 + g*4 + (m&3)]
// = w_x[m][g]; a float4 at (mb, g) holds w_x[4mb..4mb+3][g]. 32 KB per
// component, 128 KB per set (4x smaller than the expanded K).
__global__ void build_base(const float* __restrict__ wr, const float* __restrict__ wi,
                           const float* __restrict__ wj, const float* __restrict__ wk,
                           float* __restrict__ B4) {
  int idx = blockIdx.x * blockDim.x + threadIdx.x;
  if (idx >= 32768) return;
  int x = idx >> 13;
  int rem = idx & 8191;          // m*128 + g
  int m = rem >> 7, g = rem & 127;
  const float* s = (x == 0) ? wr : (x == 1) ? wi : (x == 2) ? wj : wk;
  B4[x * 8192 + (m >> 2) * 512 + g * 4 + (m & 3)] = s[rem];
}

__global__ void build_bias(const float* __restrict__ b1, const float* __restrict__ b2,
                           const float* __restrict__ b3, const float* __restrict__ b4,
                           float* __restrict__ bA, float* __restrict__ bP) {
  int i = blockIdx.x * blockDim.x + threadIdx.x;
  if (i < 512) { bA[i] = b1[i] + b2[i]; bP[i] = b3[i] + b4[i]; }
}

// X2[m][n] = sum_k A[m][k]*W[k][n] + bA[n];  A:[M][256], W:[256][512]
__global__ __launch_bounds__(256) void gemm_x2(
    const float* __restrict__ A, const float* __restrict__ W,
    const float* __restrict__ bA, float* __restrict__ C) {
  __shared__ float As[16][68];
  __shared__ float Ws[16][68];
  const int tid = threadIdx.x;
  const int nt = blockIdx.x, mt = blockIdx.y;
  const int m0 = mt * 64, n0 = nt * 64;
  const int tx = tid & 15, ty = tid >> 4;
  float acc[4][4];
#pragma unroll
  for (int i = 0; i < 4; i++)
#pragma unroll
    for (int j = 0; j < 4; j++) acc[i][j] = 0.f;
  const int lr = tid >> 2, lk = (tid & 3) * 4;
  const int wkr = tid >> 4, wn = (tid & 15) * 4;
  for (int k0 = 0; k0 < 256; k0 += 16) {
    float4 a4 = *(const float4*)(A + (size_t)(m0 + lr) * 256 + k0 + lk);
    float4 w4 = *(const float4*)(W + (size_t)(k0 + wkr) * 512 + n0 + wn);
    As[lk + 0][lr] = a4.x; As[lk + 1][lr] = a4.y; As[lk + 2][lr] = a4.z; As[lk + 3][lr] = a4.w;
    *(float4*)(&Ws[wkr][wn]) = w4;
    __syncthreads();
#pragma unroll
    for (int k = 0; k < 16; k++) {
      F4 av, wv;
      av.v = *(const float4*)(&As[k][ty * 4]);
      wv.v = *(const float4*)(&Ws[k][tx * 4]);
#pragma unroll
      for (int i = 0; i < 4; i++)
#pragma unroll
        for (int j = 0; j < 4; j++) acc[i][j] = __builtin_fmaf(av.f[i], wv.f[j], acc[i][j]);
    }
    __syncthreads();
  }
  F4 b4; b4.v = *(const float4*)(bA + n0 + tx * 4);
#pragma unroll
  for (int i = 0; i < 4; i++) {
    int m = m0 + ty * 4 + i;
    F4 o;
#pragma unroll
    for (int j = 0; j < 4; j++) o.f[j] = acc[i][j] + b4.f[j];
    *(float4*)(C + (size_t)m * 512 + n0 + tx * 4) = o.v;
  }
}

// Hamilton combine from unsigned products P[a][x] = sum_m h[a][m]*w_x[m][g]:
//   c=0 (col_r): +P[0][0] -P[1][1] -P[2][2] -P[3][3]
//   c=1 (col_i): +P[0][1] +P[1][0] -P[2][3] +P[3][2]
//   c=2 (col_j): +P[0][2] +P[1][3] +P[2][0] -P[3][1]
//   c=3 (col_k): +P[0][3] -P[1][2] +P[2][1] +P[3][0]
// (matches _qkernel's [col_r|col_i|col_j|col_k] expansion.)
#define QCOMBINE(P, o)                                              \
  do {                                                              \
    o[0] = ((P[0][0] - P[1][1]) - P[2][2]) - P[3][3];               \
    o[1] = ((P[0][1] + P[1][0]) - P[2][3]) + P[3][2];               \
    o[2] = ((P[0][2] + P[1][3]) + P[2][0]) - P[3][1];               \
    o[3] = ((P[0][3] - P[1][2]) + P[2][1]) + P[3][0];               \
  } while (0)

// State-stationary recurrent kernel, base-weight streaming, D-accumulator
// form (pure FMA inner loops; Hamilton signs applied once per thread in
// QCOMBINE — no fmul-by-±1 in the hot loop). 256 blocks x 512 threads;
// each block owns ONE batch row end-to-end: no inter-block communication.
// Bhh/Bph (256 KB) stream from L2 each step; Bpc (128 KB) is cached in
// LDS. State lives in 16 KB LDS; total 144 KB -> 1 block/CU, 8 waves.
__global__ __launch_bounds__(512, 1) void qru_rows(
    const float* __restrict__ X2,   // [steps][B][512]
    const float* __restrict__ h_in, // [B][256] raw h
    const float* __restrict__ Bhh, const float* __restrict__ Bph,
    const float* __restrict__ Bpc, const float* __restrict__ bP,
    float* __restrict__ h_out, float* __restrict__ out, float* __restrict__ hT,
    int steps) {
  __shared__ __align__(16) float hN[256];
  __shared__ __align__(16) float cnd[256];
  __shared__ __align__(16) float acL[512];
  __shared__ __align__(16) float phL[512];
  __shared__ __align__(16) float updL[512];
  __shared__ __align__(16) float pac[2048];    // partial scratch, 8 KB
  __shared__ __align__(16) float BpcL[32768];  // Kpc base set, 128 KB

  const int tid = threadIdx.x;
  const int row = blockIdx.x;
  const int g   = tid & 127;
  const int hi  = tid >> 7;          // 0..3
  const int mat = hi >> 1;           // P1: which matrix (Bhh/Bph)
  const int kq  = hi & 1;            // P1: m-half
  const int fm  = hi >> 1;           // finalize: ac vs ph
  const int fc2 = hi & 1;            // finalize: c-pair

  const float* Wp1 = ((mat == 0) ? Bhh : Bph) + (size_t)kq * 4096 + (size_t)g * 4;

  // biases for the finalize role (constant over t)
  float bpv[2] = { bP[(fc2 * 2 + 0) * 128 + g], bP[(fc2 * 2 + 1) * 128 + g] };

  // ---- stage Bpc -> LDS, relayout to [mbk*4+x][g] granules so P2b's 16
  // reads share one base address with imm offsets ----
  for (int i = tid; i < 8192; i += 512) {
    int x = i >> 11, mbk = (i >> 7) & 15, g2 = i & 127;
    *(float4*)(&BpcL[((mbk * 4 + x) * 128 + g2) * 4]) =
        *(const float4*)(Bpc + (size_t)i * 4);
  }
  // ---- init hN = normalize(h_in) ----
  if (tid < 64) {
    float v[4]; float ss = 0.f;
#pragma unroll
    for (int a = 0; a < 4; a++) {
      v[a] = h_in[(size_t)row * 256 + a * 64 + tid];
      ss += v[a] * v[a];
    }
    float inv = 1.f / (sqrtf(ss) + EPSQ);
#pragma unroll
    for (int a = 0; a < 4; a++) hN[a * 64 + tid] = v[a] * inv;
  }
  __syncthreads();

  const float* WcL = &BpcL[(size_t)(hi * 16) * 512 + g * 4];  // P2b LDS base

  for (int t = 0; t < steps; ++t) {
    // prefetch X2 additive term (fm==0 finalize threads); overlaps P1 FMAs
    float x2v[2] = {0.f, 0.f};
    if (fm == 0) {
#pragma unroll
      for (int cc = 0; cc < 2; cc++)
        x2v[cc] = X2[((size_t)t * BB + row) * 512 + (fc2 * 2 + cc) * 128 + g];
    }
    // ===== P1 partial: D[a][x] over m in [kq*32, kq*32+32) ==============
    {
      float D[4][4] = {};
#pragma unroll
      for (int mb = 0; mb < 8; mb++) {
        F4 w[4];
#pragma unroll
        for (int x = 0; x < 4; x++)
          w[x].v = *(const float4*)(Wp1 + (size_t)x * 8192 + mb * 512);
#pragma unroll
        for (int a = 0; a < 4; a++) {
          F4 h4; h4.v = *(const float4*)(&hN[a * 64 + kq * 32 + mb * 4]);
#pragma unroll
          for (int x = 0; x < 4; x++)
#pragma unroll
            for (int dk = 0; dk < 4; dk++)
              D[a][x] = __builtin_fmaf(h4.f[dk], w[x].f[dk], D[a][x]);
        }
      }
      float o[4];
      QCOMBINE(D, o);
#pragma unroll
      for (int c = 0; c < 4; c++) pac[(hi * 4 + c) * 128 + g] = o[c];
    }
    __syncthreads();
    // ===== P1 finalize: ac -> acL (+X2), ph -> phL (+bias) ==============
    {
#pragma unroll
      for (int cc = 0; cc < 2; cc++) {
        const int c = fc2 * 2 + cc;
        float s = pac[((fm * 2 + 0) * 4 + c) * 128 + g]
                + pac[((fm * 2 + 1) * 4 + c) * 128 + g];
        if (fm == 0) acL[c * 128 + g] = s + x2v[cc];
        else         phL[c * 128 + g] = s + bpv[cc];
      }
    }
    __syncthreads();
    // ===== P2a: cand_t (pointwise, 64 threads) ==========================
    if (tid < 64) {
      float am[4], cv[4];
#pragma unroll
      for (int a = 0; a < 4; a++) {
        am[a] = acL[a * 128 + tid];
        cv[a] = acL[a * 128 + 64 + tid];
      }
      float ag = sqrtf(am[0] * am[0] + am[1] * am[1] + am[2] * am[2] + am[3] * am[3]);
      float c0 = cv[0] * ag, c1 = cv[1] * ag, c2 = cv[2] * ag, c3 = cv[3] * ag;
      float mc = sqrtf(c0 * c0 + c1 * c1 + c2 * c2 + c3 * c3);
      float inv = 1.f / (mc + EPSQ);
      cnd[0 * 64 + tid] = c0 * inv;
      cnd[1 * 64 + tid] = c1 * inv;
      cnd[2 * 64 + tid] = c2 * inv;
      cnd[3 * 64 + tid] = c3 * inv;
    }
    __syncthreads();
    // ===== P2b partial: E[a][x] over m in [hi*16, hi*16+16), Kpc in LDS =
    {
      float E[4][4] = {};
#pragma unroll
      for (int mb = 0; mb < 4; mb++) {
#pragma unroll
        for (int a = 0; a < 4; a++) {
          F4 c4; c4.v = *(const float4*)(&cnd[a * 64 + hi * 16 + mb * 4]);
#pragma unroll
          for (int x = 0; x < 4; x++) {
            F4 w; w.v = *(const float4*)(WcL + (mb * 4 + x) * 512);
#pragma unroll
            for (int dk = 0; dk < 4; dk++)
              E[a][x] = __builtin_fmaf(c4.f[dk], w.f[dk], E[a][x]);
          }
        }
      }
      float o[4];
      QCOMBINE(E, o);
#pragma unroll
      for (int c = 0; c < 4; c++) pac[(hi * 4 + c) * 128 + g] = o[c];
    }
    __syncthreads();
    // ===== P2b finalize: updL = phL + sum of 4 partials =================
    {
      float s = phL[hi * 128 + g];
#pragma unroll
      for (int k8 = 0; k8 < 4; k8++) s += pac[(k8 * 4 + hi) * 128 + g];
      updL[hi * 128 + g] = s;
    }
    __syncthreads();
    // ===== P3: a_new, output, renormalize (64 threads) ==================
    if (tid < 64) {
      float u0 = updL[0 * 64 + tid];
      float u1 = updL[1 * 64 + tid];
      float u2 = updL[2 * 64 + tid];
      float u3 = updL[3 * 64 + tid];
      float u4 = updL[4 * 64 + tid];
      float u5 = updL[5 * 64 + tid];
      float u7 = updL[7 * 64 + tid];
      float mh = sqrtf(u0 * u0 + 2.f * u2 * u2 + u4 * u4);
      float mc = sqrtf(u1 * u1 + u3 * u3 + u5 * u5 + u7 * u7);
      float av[4]; float s = 0.f;
#pragma unroll
      for (int a = 0; a < 4; a++) {
        av[a] = hN[a * 64 + tid] * mh + cnd[a * 64 + tid] * mc;
        s += av[a] * av[a];
      }
      float inv = 1.f / (sqrtf(s) + EPSQ);
      float* op = out + ((size_t)t * BB + row) * 256 + tid;
#pragma unroll
      for (int a = 0; a < 4; a++) op[a * 64] = av[a];
      if (t == steps - 1) {
        float* hp = h_out + (size_t)row * 256 + tid;
#pragma unroll
        for (int a = 0; a < 4; a++) hp[a * 64] = av[a];
        if (hT != nullptr) {
          float* tp = hT + (size_t)row * 256 + tid;
#pragma unroll
          for (int a = 0; a < 4; a++) tp[a * 64] = av[a];
        }
      }
#pragma unroll
      for (int a = 0; a < 4; a++) hN[a * 64 + tid] = av[a] * inv;
    }
    __syncthreads();
  }
}

extern "C" void kernel_launch(void* const* d_in, const int* in_sizes, int n_in,
                              void* d_out, int out_size, void* d_ws, size_t ws_size,
                              hipStream_t stream) {
  const float* input = (const float*)d_in[0];
  const float* hx = (const float*)d_in[1];
  float* ws = (float*)d_ws;
  float* Kih = ws + OFF_KIH;
  float* Bhh = ws + OFF_BHH;
  float* Bph = ws + OFF_BPH;
  float* Bpc = ws + OFF_BPC;
  float* bA = ws + OFF_BA;
  float* bP = ws + OFF_BP;
  float* Hst = ws + OFF_H;
  float* X2b = ws + OFF_X2;

  build_qk<<<512, 256, 0, stream>>>((const float*)d_in[2], (const float*)d_in[3],
                                    (const float*)d_in[4], (const float*)d_in[5], Kih);
  build_base<<<128, 256, 0, stream>>>((const float*)d_in[6], (const float*)d_in[7],
                                      (const float*)d_in[8], (const float*)d_in[9], Bhh);
  build_base<<<128, 256, 0, stream>>>((const float*)d_in[10], (const float*)d_in[11],
                                      (const float*)d_in[12], (const float*)d_in[13], Bpc);
  build_base<<<128, 256, 0, stream>>>((const float*)d_in[14], (const float*)d_in[15],
                                      (const float*)d_in[16], (const float*)d_in[17], Bph);
  build_bias<<<2, 256, 0, stream>>>((const float*)d_in[18], (const float*)d_in[19],
                                    (const float*)d_in[20], (const float*)d_in[21], bA, bP);

  // pick largest chunk of steps whose X2 buffer fits in ws
  int CHv = 64;
  while (CHv > 8 && ((size_t)OFF_X2 + (size_t)CHv * BB * NC) * 4 > ws_size) CHv >>= 1;
  const int nch = S_TOT / CHv;

  for (int c = 0; c < nch; ++c) {
    gemm_x2<<<dim3(8, CHv * 4), 256, 0, stream>>>(
        input + (size_t)c * CHv * BB * DH, Kih, bA, X2b);

    const float* hsrc = (c == 0) ? hx : (const float*)Hst;
    float* outp = (float*)d_out + (size_t)c * CHv * BB * DH;
    float* hTp = (c == nch - 1) ? ((float*)d_out + (size_t)S_TOT * BB * DH) : nullptr;
    qru_rows<<<dim3(BB), dim3(512), 0, stream>>>(
        X2b, hsrc, Bhh, Bph, Bpc, bP, Hst, outp, hTp, CHv);
  }
}